// Round 5
// baseline (512.772 us; speedup 1.0000x reference)
//
#include <hip/hip_runtime.h>

#define EG   16000   // graph edges
#define NG   1000    // graph_size (block rows/cols)
#define BB   32      // batch
#define SIZE 16000   // feature length (NG*16)
#define CAP  64      // bin capacity (Poisson(16): P(>64) < 1e-17, guarded)

#define PREP_BLOCKS 4000                  // 4 tiles per block
#define EXTRACT_BLOCKS ((EG + 255) / 256) // 63

// ---- fused node 1: sample weights into TRANSPOSED vT + extract headers ----
// prep part: vT[e*256 + j*16 + i] = fma(ew[e*256+i*16+j], exp(wlv[.]), wm[.])
// Per lane: 12 full-line coalesced scalar reads, 1 float4 store. BW-bound.
__global__ __launch_bounds__(256) void prep_extract_kernel(
    const float* __restrict__ wm, const float* __restrict__ wlv,
    const float* __restrict__ ew, const int* __restrict__ rows,
    const int* __restrict__ cols, float* __restrict__ vT,
    int* __restrict__ t01)
{
    int blk = blockIdx.x;
    int tid = threadIdx.x;
    if (blk < PREP_BLOCKS) {
        int e = (blk << 2) + (tid >> 6);      // tile index
        int l = tid & 63;
        int obase = (e << 8) + (l << 2);      // output: j = l>>2, i = 4*(l&3)+k
        int ibase = (e << 8) + ((l & 3) << 6) + (l >> 2);  // input i*16+j
        float4 r;
        float m, lv, ep;
        m = wm[ibase];      lv = wlv[ibase];      ep = ew[ibase];
        r.x = fmaf(ep, __expf(lv), m);
        m = wm[ibase + 16]; lv = wlv[ibase + 16]; ep = ew[ibase + 16];
        r.y = fmaf(ep, __expf(lv), m);
        m = wm[ibase + 32]; lv = wlv[ibase + 32]; ep = ew[ibase + 32];
        r.z = fmaf(ep, __expf(lv), m);
        m = wm[ibase + 48]; lv = wlv[ibase + 48]; ep = ew[ibase + 48];
        r.w = fmaf(ep, __expf(lv), m);
        *(float4*)(vT + obase) = r;
    } else {
        int e = (blk - PREP_BLOCKS) * 256 + tid;
        if (e < EG) {
            int t0 = rows[e << 8] >> 4;       // rows[e*256] = t0*16
            int t1 = cols[e << 8] >> 4;
            t01[e] = (t0 << 10) | t1;
        }
    }
}

// ---- node 2: deterministic ballot-compaction binning (no atomics) ----
__global__ __launch_bounds__(64) void build_kernel(const int* __restrict__ t01,
                                                   int* __restrict__ bins,
                                                   int* __restrict__ edge_of) {
    int g    = blockIdx.x;
    int lane = threadIdx.x;                  // EG = 64*250 exact
    int cnt  = 0;
    #pragma unroll 4
    for (int ebase = 0; ebase < EG; ebase += 64) {
        int e  = ebase + lane;
        int pk = t01[e];
        bool m = (pk >> 10) == g;
        unsigned long long mask = __ballot(m);
        if (m) {
            int slot = cnt + __popcll(mask & ((1ull << lane) - 1ull));
            if (slot < CAP)
                edge_of[(g << 6) + slot] = e | ((pk & 1023) << 16);
        }
        cnt += __popcll(mask);
    }
    if (lane == 0) bins[g] = (cnt < CAP) ? cnt : CAP;
}

// ---- node 3: spmm. 2 workgroups per bin (batch halves), 256 threads.
// Thread (j = tid&15, b0 = tid>>4) owns output (batch = half*16+b0, j).
// Per edge: 4 float4 vT loads (contiguous column) + 4 float4 x loads,
// register double-buffered; headers broadcast from registers via shfl.
// No LDS, no barriers, no atomics.
__global__ __launch_bounds__(256) void spmm_kernel(
    const float* __restrict__ vT, const float* __restrict__ x,
    const float* __restrict__ bm, const float* __restrict__ blv,
    const float* __restrict__ eb, const int* __restrict__ bins,
    const int* __restrict__ edge_of, float* __restrict__ out)
{
    int g    = blockIdx.x >> 1;
    int half = blockIdx.x & 1;
    int tid  = threadIdx.x;
    int j    = tid & 15;
    int b0   = tid >> 4;                     // 0..15
    int batch = (half << 4) + b0;

    int n = bins[g];
    // one coalesced load of the whole bin's headers; slots >= n unused
    int hreg = edge_of[(g << 6) + (tid & 63)];

    const float* xrow = x + batch * SIZE;

    float4 V[2][4], X[2][4];
    float acc = 0.f;

    #define ISSUE(p, buf)                                                     \
        {                                                                     \
            int hh = __shfl(hreg, (p));                                       \
            const float4* vp = (const float4*)(vT + ((hh & 0xFFFF) << 8)      \
                                               + (j << 4));                   \
            const float4* xp = (const float4*)(xrow + ((hh >> 16) << 4));     \
            V[buf][0] = vp[0]; V[buf][1] = vp[1];                             \
            V[buf][2] = vp[2]; V[buf][3] = vp[3];                             \
            X[buf][0] = xp[0]; X[buf][1] = xp[1];                             \
            X[buf][2] = xp[2]; X[buf][3] = xp[3];                             \
        }

    if (n > 0) ISSUE(0, 0);
    for (int p = 0; p < n; ++p) {
        int cur = p & 1;
        if (p + 1 < n) ISSUE(p + 1, cur ^ 1);
        const float* vv = (const float*)V[cur];
        const float* xx = (const float*)X[cur];
        #pragma unroll
        for (int i = 0; i < 16; ++i)
            acc = fmaf(vv[i], xx[i], acc);
    }
    #undef ISSUE

    int r = (g << 4) + j;
    float bias = fmaf(eb[r], __expf(blv[r]), bm[r]);
    out[batch * SIZE + r] = acc + bias;
    if (blockIdx.x == 0 && tid == 0) out[BB * SIZE] = 0.0f;   // kl scalar
}

extern "C" void kernel_launch(void* const* d_in, const int* in_sizes, int n_in,
                              void* d_out, int out_size, void* d_ws, size_t ws_size,
                              hipStream_t stream) {
    const float* x   = (const float*)d_in[0];
    const float* wm  = (const float*)d_in[1];
    const float* wlv = (const float*)d_in[2];
    const float* bm  = (const float*)d_in[3];
    const float* blv = (const float*)d_in[4];
    const float* ew  = (const float*)d_in[5];
    const float* eb  = (const float*)d_in[6];
    const int* rows  = (const int*)d_in[7];
    const int* cols  = (const int*)d_in[8];
    float* out = (float*)d_out;

    char* ws = (char*)d_ws;
    int*   t01     = (int*)(ws);             // 16000 ints (64 KB)
    int*   bins    = (int*)(ws + 65536);     // 1000 ints
    int*   edge_of = (int*)(ws + 69632);     // 64000 ints (256 KB)
    float* vT      = (float*)(ws + 524288);  // NNZ floats (16.4 MB)

    prep_extract_kernel<<<PREP_BLOCKS + EXTRACT_BLOCKS, 256, 0, stream>>>(
        wm, wlv, ew, rows, cols, vT, t01);
    build_kernel<<<NG, 64, 0, stream>>>(t01, bins, edge_of);
    spmm_kernel<<<NG * 2, 256, 0, stream>>>(vT, x, bm, blv, eb,
                                            bins, edge_of, out);
}

// Round 6
// 243.943 us; speedup vs baseline: 2.1020x; 2.1020x over previous
//
#include <hip/hip_runtime.h>

#define EG   16000   // graph edges
#define NG   1000    // graph_size (block rows/cols)
#define BB   32      // batch
#define SIZE 16000   // feature length (NG*16)
#define CAP  64      // bin capacity (Poisson(16): P(>64) < 1e-17, guarded)

#define PREP_BLOCKS 4000                  // 4 tiles per block
#define EXTRACT_BLOCKS ((EG + 255) / 256) // 63

// ---- fused node 1: sample weights into TRANSPOSED vT + extract headers ----
// prep part: vT[e*256 + j*16 + i] = fma(ew[e*256+i*16+j], exp(wlv[.]), wm[.])
__global__ __launch_bounds__(256) void prep_extract_kernel(
    const float* __restrict__ wm, const float* __restrict__ wlv,
    const float* __restrict__ ew, const int* __restrict__ rows,
    const int* __restrict__ cols, float* __restrict__ vT,
    int* __restrict__ t01)
{
    int blk = blockIdx.x;
    int tid = threadIdx.x;
    if (blk < PREP_BLOCKS) {
        int e = (blk << 2) + (tid >> 6);      // tile index
        int l = tid & 63;
        int obase = (e << 8) + (l << 2);      // output: j = l>>2, i = 4*(l&3)+k
        int ibase = (e << 8) + ((l & 3) << 6) + (l >> 2);  // input i*16+j
        float4 r;
        float m, lv, ep;
        m = wm[ibase];      lv = wlv[ibase];      ep = ew[ibase];
        r.x = fmaf(ep, __expf(lv), m);
        m = wm[ibase + 16]; lv = wlv[ibase + 16]; ep = ew[ibase + 16];
        r.y = fmaf(ep, __expf(lv), m);
        m = wm[ibase + 32]; lv = wlv[ibase + 32]; ep = ew[ibase + 32];
        r.z = fmaf(ep, __expf(lv), m);
        m = wm[ibase + 48]; lv = wlv[ibase + 48]; ep = ew[ibase + 48];
        r.w = fmaf(ep, __expf(lv), m);
        *(float4*)(vT + obase) = r;
    } else {
        int e = (blk - PREP_BLOCKS) * 256 + tid;
        if (e < EG) {
            int t0 = rows[e << 8] >> 4;       // rows[e*256] = t0*16
            int t1 = cols[e << 8] >> 4;
            t01[e] = (t0 << 10) | t1;
        }
    }
}

// ---- node 2: deterministic ballot-compaction binning (no atomics) ----
__global__ __launch_bounds__(64) void build_kernel(const int* __restrict__ t01,
                                                   int* __restrict__ bins,
                                                   int* __restrict__ edge_of) {
    int g    = blockIdx.x;
    int lane = threadIdx.x;                  // EG = 64*250 exact
    int cnt  = 0;
    #pragma unroll 4
    for (int ebase = 0; ebase < EG; ebase += 64) {
        int e  = ebase + lane;
        int pk = t01[e];
        bool m = (pk >> 10) == g;
        unsigned long long mask = __ballot(m);
        if (m) {
            int slot = cnt + __popcll(mask & ((1ull << lane) - 1ull));
            if (slot < CAP)
                edge_of[(g << 6) + slot] = e | ((pk & 1023) << 16);
        }
        cnt += __popcll(mask);
    }
    if (lane == 0) bins[g] = (cnt < CAP) ? cnt : CAP;
}

// ---- node 3: spmm. 2 workgroups per bin (batch halves), 256 threads.
// Thread (j = tid&15, b0 = tid>>4) owns output (batch = half*16+b0, j).
// Per edge: 4 float4 vT loads (contiguous column) + 4 float4 x loads.
// Register double-buffer uses NAMED float4 variables + manual 2x unroll —
// all buffer references are compile-time registers (R5's dynamic V[cur]
// indexing spilled to scratch: 941 MB WRITE_SIZE, VGPR=24).
__global__ __launch_bounds__(256) void spmm_kernel(
    const float* __restrict__ vT, const float* __restrict__ x,
    const float* __restrict__ bm, const float* __restrict__ blv,
    const float* __restrict__ eb, const int* __restrict__ bins,
    const int* __restrict__ edge_of, float* __restrict__ out)
{
    int g    = blockIdx.x >> 1;
    int half = blockIdx.x & 1;
    int tid  = threadIdx.x;
    int j    = tid & 15;
    int b0   = tid >> 4;                     // 0..15
    int batch = (half << 4) + b0;

    int n = bins[g];
    // one coalesced load of the whole bin's headers, broadcast via shfl
    int hreg = edge_of[(g << 6) + (tid & 63)];

    const float* xrow = x + batch * SIZE;

    float4 Va0, Va1, Va2, Va3, Xa0, Xa1, Xa2, Xa3;
    float4 Vb0, Vb1, Vb2, Vb3, Xb0, Xb1, Xb2, Xb3;
    float acc = 0.f;

    #define ISSUE(p, V0, V1, V2, V3, X0, X1, X2, X3)                          \
        {                                                                     \
            int hh = __shfl(hreg, (p));                                       \
            const float4* vp = (const float4*)(vT + ((hh & 0xFFFF) << 8)      \
                                               + (j << 4));                   \
            const float4* xp = (const float4*)(xrow + ((hh >> 16) << 4));     \
            V0 = vp[0]; V1 = vp[1]; V2 = vp[2]; V3 = vp[3];                   \
            X0 = xp[0]; X1 = xp[1]; X2 = xp[2]; X3 = xp[3];                   \
        }

    #define FMA16(V0, V1, V2, V3, X0, X1, X2, X3)                             \
        {                                                                     \
            acc = fmaf(V0.x, X0.x, acc); acc = fmaf(V0.y, X0.y, acc);         \
            acc = fmaf(V0.z, X0.z, acc); acc = fmaf(V0.w, X0.w, acc);         \
            acc = fmaf(V1.x, X1.x, acc); acc = fmaf(V1.y, X1.y, acc);         \
            acc = fmaf(V1.z, X1.z, acc); acc = fmaf(V1.w, X1.w, acc);         \
            acc = fmaf(V2.x, X2.x, acc); acc = fmaf(V2.y, X2.y, acc);         \
            acc = fmaf(V2.z, X2.z, acc); acc = fmaf(V2.w, X2.w, acc);         \
            acc = fmaf(V3.x, X3.x, acc); acc = fmaf(V3.y, X3.y, acc);         \
            acc = fmaf(V3.z, X3.z, acc); acc = fmaf(V3.w, X3.w, acc);         \
        }

    if (n > 0) ISSUE(0, Va0, Va1, Va2, Va3, Xa0, Xa1, Xa2, Xa3);
    int p = 0;
    while (p < n) {
        if (p + 1 < n) ISSUE(p + 1, Vb0, Vb1, Vb2, Vb3, Xb0, Xb1, Xb2, Xb3);
        FMA16(Va0, Va1, Va2, Va3, Xa0, Xa1, Xa2, Xa3);
        ++p;
        if (p >= n) break;
        if (p + 1 < n) ISSUE(p + 1, Va0, Va1, Va2, Va3, Xa0, Xa1, Xa2, Xa3);
        FMA16(Vb0, Vb1, Vb2, Vb3, Xb0, Xb1, Xb2, Xb3);
        ++p;
    }
    #undef ISSUE
    #undef FMA16

    int r = (g << 4) + j;
    float bias = fmaf(eb[r], __expf(blv[r]), bm[r]);
    out[batch * SIZE + r] = acc + bias;
    if (blockIdx.x == 0 && tid == 0) out[BB * SIZE] = 0.0f;   // kl scalar
}

extern "C" void kernel_launch(void* const* d_in, const int* in_sizes, int n_in,
                              void* d_out, int out_size, void* d_ws, size_t ws_size,
                              hipStream_t stream) {
    const float* x   = (const float*)d_in[0];
    const float* wm  = (const float*)d_in[1];
    const float* wlv = (const float*)d_in[2];
    const float* bm  = (const float*)d_in[3];
    const float* blv = (const float*)d_in[4];
    const float* ew  = (const float*)d_in[5];
    const float* eb  = (const float*)d_in[6];
    const int* rows  = (const int*)d_in[7];
    const int* cols  = (const int*)d_in[8];
    float* out = (float*)d_out;

    char* ws = (char*)d_ws;
    int*   t01     = (int*)(ws);             // 16000 ints (64 KB)
    int*   bins    = (int*)(ws + 65536);     // 1000 ints
    int*   edge_of = (int*)(ws + 69632);     // 64000 ints (256 KB)
    float* vT      = (float*)(ws + 524288);  // NNZ floats (16.4 MB)

    prep_extract_kernel<<<PREP_BLOCKS + EXTRACT_BLOCKS, 256, 0, stream>>>(
        wm, wlv, ew, rows, cols, vT, t01);
    build_kernel<<<NG, 64, 0, stream>>>(t01, bins, edge_of);
    spmm_kernel<<<NG * 2, 256, 0, stream>>>(vT, x, bm, blv, eb,
                                            bins, edge_of, out);
}